// Round 9
// baseline (2970.328 us; speedup 1.0000x reference)
//
#include <hip/hip_runtime.h>

// Problem constants
#define Bn 4
#define Nn 8192
#define Dn 64
#define Sn 2048
#define Kn 32
#define R2c 0.04f          // f32(0.2*0.2) — same bits as np/jax weak-scalar cast
#define OUT_XYZ (Bn*Sn*3)  // 24576 floats of new_xyz, then feats

// Workspace layout (units = 4-byte elements)
#define WS_P4  0            // [B*N] float4 {x,y,z,0}
#define WS_W1T 131072       // W1^T [67][64]
#define WS_W2T 135360       // W2^T [64][128]
#define WS_W3T 143552       // W3^T [128][256]
#define WS_GRP 176320       // int grp_idx [B*S][K]

#define KPAD 36             // padded LDS row stride (floats) for h tiles

// ---------------------------------------------------------------------------
// Prep: xyz -> float4 array and weights -> [C][O] layout
// ---------------------------------------------------------------------------
__global__ __launch_bounds__(256) void prep_kernel(const float* __restrict__ xyz,
                                                   const float* __restrict__ W1,
                                                   const float* __restrict__ W2,
                                                   const float* __restrict__ W3,
                                                   float* __restrict__ ws) {
    int id = blockIdx.x * 256 + threadIdx.x;
    if (id < Bn * Nn) {
        float4* p4 = (float4*)(ws + WS_P4);
        p4[id] = make_float4(xyz[id * 3 + 0], xyz[id * 3 + 1], xyz[id * 3 + 2], 0.f);
    }
    int i1 = id - Bn * Nn;
    if (i1 >= 0 && i1 < 64 * 67)  { int o = i1 / 67,  c = i1 % 67;  ws[WS_W1T + c * 64  + o] = W1[i1]; }
    int i2 = i1 - 64 * 67;
    if (i2 >= 0 && i2 < 128 * 64) { int o = i2 / 64,  c = i2 % 64;  ws[WS_W2T + c * 128 + o] = W2[i2]; }
    int i3 = i2 - 128 * 64;
    if (i3 >= 0 && i3 < 256 * 128){ int o = i3 / 128, c = i3 % 128; ws[WS_W3T + c * 256 + o] = W3[i3]; }
}

// DPP wave-64 max: row_shr 1/2/4/8 (within 16-lane rows) -> lane15/31/47/63
// hold row maxima; row_bcast15 + row_bcast31 merge rows -> lane 63 = full max.
// bound_ctrl=true injects 0 for invalid lanes (harmless: dist >= 0).
__device__ __forceinline__ float wave_fmax_dpp(float x) {
    float t;
    t = __int_as_float(__builtin_amdgcn_update_dpp(0, __float_as_int(x), 0x111, 0xf, 0xf, true)); x = fmaxf(x, t);
    t = __int_as_float(__builtin_amdgcn_update_dpp(0, __float_as_int(x), 0x112, 0xf, 0xf, true)); x = fmaxf(x, t);
    t = __int_as_float(__builtin_amdgcn_update_dpp(0, __float_as_int(x), 0x114, 0xf, 0xf, true)); x = fmaxf(x, t);
    t = __int_as_float(__builtin_amdgcn_update_dpp(0, __float_as_int(x), 0x118, 0xf, 0xf, true)); x = fmaxf(x, t);
    t = __int_as_float(__builtin_amdgcn_update_dpp(0, __float_as_int(x), 0x142, 0xf, 0xf, true)); x = fmaxf(x, t);
    t = __int_as_float(__builtin_amdgcn_update_dpp(0, __float_as_int(x), 0x143, 0xf, 0xf, true)); x = fmaxf(x, t);
    return __int_as_float(__builtin_amdgcn_readlane(__float_as_int(x), 63));
}

// ---------------------------------------------------------------------------
// Farthest point sampling — value-only hot path, ONE barrier per step.
// __launch_bounds__(512, 2): grid is 4 workgroups (1/CU), so 2 waves/SIMD is
// the ceiling anyway; declaring it raises the VGPR cap to 256 so the 64-float
// point/dist working set stays IN REGISTERS (R3..R8 ran at 48-68 VGPRs ->
// scratch-spilled every step — the hidden flat ~2850 cyc/step).
//   * distance math mirrors numpy bit-exactly: separate mul/add,
//     (dx*dx+dy*dy)+dz*dz, fminf, contract off. fmax reduce order-invariant.
//   * index recovery rare-path per wave; lane0 packs (val|~p) key to LDS;
//     one __syncthreads; all threads scan 8 keys; uniform float4 L2 load.
//   * centroid history in LDS, coalesced dump at end.
// One workgroup per batch, 512 threads, 16 pts/thread in registers.
// ---------------------------------------------------------------------------
__global__ __launch_bounds__(512, 2) void fps_kernel(const float* __restrict__ ws,
                                                     float* __restrict__ out_xyz) {
    #pragma clang fp contract(off)
    const int b = blockIdx.x;
    const int tid = threadIdx.x;
    const float4* p4 = (const float4*)(ws + WS_P4) + b * Nn;

    float px[16], py[16], pz[16], dist[16];
    #pragma unroll
    for (int j = 0; j < 16; j++) {
        float4 v = p4[j * 512 + tid];    // coalesced 16B/lane
        px[j] = v.x; py[j] = v.y; pz[j] = v.z;
        dist[j] = 1e10f;                 // matches np.float32(1e10)
    }

    __shared__ unsigned long long sKey[2][8];
    __shared__ float sHist[Sn * 3];

    // initial centroid = point 0 of the batch (uniform load, once)
    float4 c0 = p4[0];
    float cx = c0.x, cy = c0.y, cz = c0.z;

    for (int s = 0; s < Sn; s++) {
        const int par = s & 1;
        if (tid == 0) {                 // record carry centroid (LDS, cheap)
            sHist[s * 3 + 0] = cx;
            sHist[s * 3 + 1] = cy;
            sHist[s * 3 + 2] = cz;
        }
        // minimal dist update: 3 sub, 3 mul, 2 add, fmin, fmax per point —
        // exact reference op order, NO index tracking
        float lv = -1.0f;
        #pragma unroll
        for (int j = 0; j < 16; j++) {
            float dx = px[j] - cx, dy = py[j] - cy, dz = pz[j] - cz;
            float d  = (dx * dx + dy * dy) + dz * dz;
            float dm = fminf(dist[j], d);
            dist[j] = dm;
            lv = fmaxf(lv, dm);
        }
        // wave max via DPP (VALU pipe, cheap)
        float wmax = wave_fmax_dpp(lv);
        // rare-path index recovery within the wave
        int pb = 0x7fffffff;
        bool match = (lv == wmax);
        if (match) {
            #pragma unroll
            for (int j = 15; j >= 0; j--)          // descending -> min p kept
                if (dist[j] == wmax) pb = j * 512 + tid;
        }
        unsigned long long mask = __ballot(match);  // >=1 lane set
        int cand;
        if (__popcll(mask) == 1) {                  // common case
            cand = __builtin_amdgcn_readlane(pb, (int)(__ffsll(mask) - 1));
        } else {                                    // exact value tie (~rare)
            int v = pb;
            #pragma unroll
            for (int off = 32; off >= 1; off >>= 1) {
                int o = __shfl_xor(v, off);
                v = o < v ? o : v;
            }
            cand = v;
        }
        if ((tid & 63) == 0) {
            sKey[par][tid >> 6] =
                ((unsigned long long)__float_as_uint(wmax) << 32) |
                (unsigned long long)(0xFFFFFFFFu - (unsigned)cand);
        }
        __syncthreads();                   // the ONLY barrier per step
        // all threads scan the 8 wave keys: max val, min p on tie
        unsigned long long k = sKey[par][0];
        #pragma unroll
        for (int i = 1; i < 8; i++) {
            unsigned long long o = sKey[par][i];
            k = (o > k) ? o : k;
        }
        int p = (int)(0xFFFFFFFFu - (unsigned)(k & 0xFFFFFFFFull));
        float4 c4 = p4[p];                 // uniform addr -> one dwordx4, L2-hot
        cx = c4.x; cy = c4.y; cz = c4.z;
    }

    __syncthreads();                       // sHist complete
    // coalesced dump: 6144 floats = 1536 float4, 3 per thread
    float4* o4 = (float4*)(out_xyz + b * Sn * 3);
    const float4* h4 = (const float4*)sHist;
    #pragma unroll
    for (int i = tid; i < Sn * 3 / 4; i += 512) o4[i] = h4[i];
}

// ---------------------------------------------------------------------------
// Ball query, f32, mirroring the numpy transpile with einsum lowered to
// BLAS sgemm: the k=3 dot is an FMA chain acc=fma(a_k,b_k,acc) from 0.
// Norm terms are plain mul/add ((x2+y2)+z2). sq = (t1+t2) - 2*dot.
// One wave per (b,s). First K hits in ascending index order via
// ballot + prefix-popcount, early exit, pad with first hit.
// ---------------------------------------------------------------------------
__global__ __launch_bounds__(256) void ballq_kernel(const float* __restrict__ ws,
                                                    const float* __restrict__ newxyz,
                                                    int* __restrict__ grp) {
    #pragma clang fp contract(off)
    int t = blockIdx.x * 256 + threadIdx.x;
    int wid = t >> 6;            // 0..8191  (b*S+s)
    int lane = t & 63;
    int b = wid >> 11;
    const float4* p4 = (const float4*)(ws + WS_P4) + b * Nn;

    float nx = newxyz[wid * 3 + 0], ny = newxyz[wid * 3 + 1], nz = newxyz[wid * 3 + 2];
    float a2 = (nx * nx + ny * ny) + nz * nz;   // np.sum(new**2, -1): plain mul/add

    int total = 0;
    int firstp = 0;
    for (int c = 0; c < Nn / 64; c++) {
        int p = c * 64 + lane;
        float4 v = p4[p];
        float x = v.x, y = v.y, z = v.z;
        float bv = (x * x + y * y) + z * z;          // np.sum(xyz**2, -1)
        // sgemm k-loop: FMA rank-1 updates in order, acc starts at 0
        float dot = __builtin_fmaf(nx, x, 0.0f);
        dot = __builtin_fmaf(ny, y, dot);
        dot = __builtin_fmaf(nz, z, dot);
        float sq = (a2 + bv) - 2.0f * dot;           // (t1+t2) - 2*e
        bool hit = !(sq > R2c);
        unsigned long long mask = __ballot(hit);
        if (mask) {
            if (total == 0) firstp = c * 64 + (__ffsll(mask) - 1);
            int rank = __popcll(mask & ((1ull << lane) - 1ull));
            int slot = total + rank;
            if (hit && slot < Kn) grp[wid * Kn + slot] = p;
            total += (int)__popcll(mask);
            if (total >= Kn) break;
        }
    }
    if (lane >= total && lane < Kn) grp[wid * Kn + lane] = firstp;  // pad w/ first hit
}

// ---------------------------------------------------------------------------
// Fused gather + 3-layer MLP + maxpool (f32 — error ~1e-5 « 0.064 budget).
// __launch_bounds__(256, 3): 45.5 KB LDS -> 3 blocks/CU max; declaring 3
// waves/EU raises the VGPR cap (~170) so acc/weight tiles don't spill.
// ---------------------------------------------------------------------------
template<int C, int O, int WO>
__device__ __forceinline__ void mlp_layer(const float* inT, float* outT,
                                          const float* __restrict__ wt,
                                          const float* __restrict__ bias,
                                          int kt, int ot) {
    float acc[4][WO];
    #pragma unroll
    for (int oo = 0; oo < WO; oo++) {
        float bb = bias[ot * WO + oo];
        #pragma unroll
        for (int kk = 0; kk < 4; kk++) acc[kk][oo] = bb;
    }
    for (int c = 0; c < C; c++) {
        float4 hv = *(const float4*)&inT[c * KPAD + kt * 4];
        float ha[4] = {hv.x, hv.y, hv.z, hv.w};
        const float* wp = wt + c * O + ot * WO;
        float wv[WO];
        if constexpr (WO == 2) {
            float2 w = *(const float2*)wp; wv[0] = w.x; wv[1] = w.y;
        } else if constexpr (WO == 4) {
            float4 w = *(const float4*)wp; wv[0] = w.x; wv[1] = w.y; wv[2] = w.z; wv[3] = w.w;
        } else {
            float4 w0 = *(const float4*)wp, w1 = *(const float4*)(wp + 4);
            wv[0] = w0.x; wv[1] = w0.y; wv[2] = w0.z; wv[3] = w0.w;
            wv[4] = w1.x; wv[5] = w1.y; wv[6] = w1.z; wv[7] = w1.w;
        }
        #pragma unroll
        for (int kk = 0; kk < 4; kk++)
            #pragma unroll
            for (int oo = 0; oo < WO; oo++) acc[kk][oo] += ha[kk] * wv[oo];
    }
    #pragma unroll
    for (int oo = 0; oo < WO; oo++) {
        int o = ot * WO + oo;
        float4 st;
        st.x = fmaxf(acc[0][oo], 0.f); st.y = fmaxf(acc[1][oo], 0.f);
        st.z = fmaxf(acc[2][oo], 0.f); st.w = fmaxf(acc[3][oo], 0.f);
        *(float4*)&outT[o * KPAD + kt * 4] = st;
    }
}

__global__ __launch_bounds__(256, 3) void mlp_kernel(const float* __restrict__ xyz,
                                                     const float* __restrict__ feat,
                                                     const float* __restrict__ ws,
                                                     const int* __restrict__ grp,
                                                     const float* __restrict__ b1,
                                                     const float* __restrict__ b2,
                                                     const float* __restrict__ b3,
                                                     float* __restrict__ out) {
    __shared__ float h0[67 * KPAD];
    __shared__ float h1[64 * KPAD];
    __shared__ float h2[128 * KPAD];
    __shared__ float mxs[8 * 256];
    __shared__ int   sIdx[Kn];
    __shared__ float sCent[3];

    int g = blockIdx.x;            // b*S + s
    int b = g >> 11;
    int tid = threadIdx.x;

    if (tid < Kn) sIdx[tid] = grp[g * Kn + tid];
    if (tid == 0) { sCent[0] = out[g*3]; sCent[1] = out[g*3+1]; sCent[2] = out[g*3+2]; }
    __syncthreads();

    { // gather: 8 threads per neighbor row
        int k = tid >> 3, m = tid & 7;
        int idx = sIdx[k];
        int base = b * Nn + idx;
        if (m == 0) {
            h0[0 * KPAD + k] = xyz[base * 3 + 0] - sCent[0];
            h0[1 * KPAD + k] = xyz[base * 3 + 1] - sCent[1];
            h0[2 * KPAD + k] = xyz[base * 3 + 2] - sCent[2];
        }
        const float4* f4 = (const float4*)(feat + base * 64 + m * 8);
        float4 a = f4[0], c4 = f4[1];
        int r = 3 + m * 8;
        h0[(r + 0) * KPAD + k] = a.x;  h0[(r + 1) * KPAD + k] = a.y;
        h0[(r + 2) * KPAD + k] = a.z;  h0[(r + 3) * KPAD + k] = a.w;
        h0[(r + 4) * KPAD + k] = c4.x; h0[(r + 5) * KPAD + k] = c4.y;
        h0[(r + 6) * KPAD + k] = c4.z; h0[(r + 7) * KPAD + k] = c4.w;
    }
    __syncthreads();

    int ot = tid & 31, kt = tid >> 5;

    mlp_layer<67, 64, 2>(h0, h1, ws + WS_W1T, b1, kt, ot);
    __syncthreads();
    mlp_layer<64, 128, 4>(h1, h2, ws + WS_W2T, b2, kt, ot);
    __syncthreads();

    { // L3 (128 -> 256) fused with maxpool over the thread's 4 k-rows
        float acc[4][8];
        #pragma unroll
        for (int oo = 0; oo < 8; oo++) {
            float bb = b3[ot * 8 + oo];
            #pragma unroll
            for (int kk = 0; kk < 4; kk++) acc[kk][oo] = bb;
        }
        const float* wt = ws + WS_W3T;
        for (int c = 0; c < 128; c++) {
            float4 hv = *(const float4*)&h2[c * KPAD + kt * 4];
            float ha[4] = {hv.x, hv.y, hv.z, hv.w};
            const float* wp = wt + c * 256 + ot * 8;
            float4 w0 = *(const float4*)wp, w1 = *(const float4*)(wp + 4);
            float wv[8] = {w0.x, w0.y, w0.z, w0.w, w1.x, w1.y, w1.z, w1.w};
            #pragma unroll
            for (int kk = 0; kk < 4; kk++)
                #pragma unroll
                for (int oo = 0; oo < 8; oo++) acc[kk][oo] += ha[kk] * wv[oo];
        }
        #pragma unroll
        for (int oo = 0; oo < 8; oo++) {
            float m = fmaxf(fmaxf(acc[0][oo], acc[1][oo]), fmaxf(acc[2][oo], acc[3][oo]));
            mxs[kt * 256 + ot * 8 + oo] = fmaxf(m, 0.f);   // relu(max) == max(relu)
        }
    }
    __syncthreads();

    { // reduce the 8 k-tiles, write feats
        int o = tid;
        float m = mxs[o];
        #pragma unroll
        for (int q = 1; q < 8; q++) m = fmaxf(m, mxs[q * 256 + o]);
        out[OUT_XYZ + g * 256 + o] = m;
    }
}

// ---------------------------------------------------------------------------
extern "C" void kernel_launch(void* const* d_in, const int* in_sizes, int n_in,
                              void* d_out, int out_size, void* d_ws, size_t ws_size,
                              hipStream_t stream) {
    const float* xyz  = (const float*)d_in[0];
    const float* feat = (const float*)d_in[1];
    const float* W1   = (const float*)d_in[2];
    const float* b1   = (const float*)d_in[3];
    const float* W2   = (const float*)d_in[4];
    const float* b2   = (const float*)d_in[5];
    const float* W3   = (const float*)d_in[6];
    const float* b3   = (const float*)d_in[7];
    float* out = (float*)d_out;
    float* ws  = (float*)d_ws;
    int*   grp = (int*)d_ws + WS_GRP;

    hipLaunchKernelGGL(prep_kernel, dim3(305), dim3(256), 0, stream, xyz, W1, W2, W3, ws);
    hipLaunchKernelGGL(fps_kernel, dim3(Bn), dim3(512), 0, stream, ws, out);
    hipLaunchKernelGGL(ballq_kernel, dim3(Bn * Sn / 4), dim3(256), 0, stream, ws, out, grp);
    hipLaunchKernelGGL(mlp_kernel, dim3(Bn * Sn), dim3(256), 0, stream,
                       xyz, feat, ws, grp, b1, b2, b3, out);
}

// Round 10
// 2945.588 us; speedup vs baseline: 1.0084x; 1.0084x over previous
//
#include <hip/hip_runtime.h>

// Problem constants
#define Bn 4
#define Nn 8192
#define Dn 64
#define Sn 2048
#define Kn 32
#define R2c 0.04f          // f32(0.2*0.2) — same bits as np/jax weak-scalar cast
#define OUT_XYZ (Bn*Sn*3)  // 24576 floats of new_xyz, then feats

// Workspace layout (units = 4-byte elements)
#define WS_P4  0            // [B*N] float4 {x,y,z,0}
#define WS_W1T 131072       // W1^T [67][64]
#define WS_W2T 135360       // W2^T [64][128]
#define WS_W3T 143552       // W3^T [128][256]
#define WS_GRP 176320       // int grp_idx [B*S][K]

#define KPAD 36             // padded LDS row stride (floats) for h tiles

// ---------------------------------------------------------------------------
// Prep: xyz -> float4 array and weights -> [C][O] layout
// ---------------------------------------------------------------------------
__global__ __launch_bounds__(256) void prep_kernel(const float* __restrict__ xyz,
                                                   const float* __restrict__ W1,
                                                   const float* __restrict__ W2,
                                                   const float* __restrict__ W3,
                                                   float* __restrict__ ws) {
    int id = blockIdx.x * 256 + threadIdx.x;
    if (id < Bn * Nn) {
        float4* p4 = (float4*)(ws + WS_P4);
        p4[id] = make_float4(xyz[id * 3 + 0], xyz[id * 3 + 1], xyz[id * 3 + 2], 0.f);
    }
    int i1 = id - Bn * Nn;
    if (i1 >= 0 && i1 < 64 * 67)  { int o = i1 / 67,  c = i1 % 67;  ws[WS_W1T + c * 64  + o] = W1[i1]; }
    int i2 = i1 - 64 * 67;
    if (i2 >= 0 && i2 < 128 * 64) { int o = i2 / 64,  c = i2 % 64;  ws[WS_W2T + c * 128 + o] = W2[i2]; }
    int i3 = i2 - 128 * 64;
    if (i3 >= 0 && i3 < 256 * 128){ int o = i3 / 128, c = i3 % 128; ws[WS_W3T + c * 256 + o] = W3[i3]; }
}

// DPP wave-64 max: row_shr 1/2/4/8 (within 16-lane rows) -> lane15/31/47/63
// hold row maxima; row_bcast15 + row_bcast31 merge rows -> lane 63 = full max.
// bound_ctrl=true injects 0 for invalid lanes (harmless: dist >= 0).
__device__ __forceinline__ float wave_fmax_dpp(float x) {
    float t;
    t = __int_as_float(__builtin_amdgcn_update_dpp(0, __float_as_int(x), 0x111, 0xf, 0xf, true)); x = fmaxf(x, t);
    t = __int_as_float(__builtin_amdgcn_update_dpp(0, __float_as_int(x), 0x112, 0xf, 0xf, true)); x = fmaxf(x, t);
    t = __int_as_float(__builtin_amdgcn_update_dpp(0, __float_as_int(x), 0x114, 0xf, 0xf, true)); x = fmaxf(x, t);
    t = __int_as_float(__builtin_amdgcn_update_dpp(0, __float_as_int(x), 0x118, 0xf, 0xf, true)); x = fmaxf(x, t);
    t = __int_as_float(__builtin_amdgcn_update_dpp(0, __float_as_int(x), 0x142, 0xf, 0xf, true)); x = fmaxf(x, t);
    t = __int_as_float(__builtin_amdgcn_update_dpp(0, __float_as_int(x), 0x143, 0xf, 0xf, true)); x = fmaxf(x, t);
    return __int_as_float(__builtin_amdgcn_readlane(__float_as_int(x), 63));
}

// ---------------------------------------------------------------------------
// Farthest point sampling — value-only hot path, ONE barrier per step.
// KEY FIX (R10): R9's VGPR_Count=56 < 64 live floats proved the compiler was
// RE-LOADING px/py/pz from memory every step (legal remat of loop-invariant
// const loads) — ~24.6 KB/WG/step through L1 ≈ 2000 cyc, the invariant floor
// behind R4-R9's flat ~2850 cyc/step. The inline-asm "+v" pins below make the
// values opaque so they MUST stay in VGPRs (cap 256 via launch_bounds(512,2),
// only ~90 live -> no spill).
//   * distance math mirrors numpy bit-exactly: separate mul/add,
//     (dx*dx+dy*dy)+dz*dz, fminf, contract off. fmax reduce order-invariant.
//   * index recovery rare-path per wave; lane0 packs (val|~p) key to LDS;
//     one __syncthreads; all threads scan 8 keys; uniform float4 L2 load.
//   * centroid history in LDS, coalesced dump at end.
// One workgroup per batch, 512 threads, 16 pts/thread in registers.
// ---------------------------------------------------------------------------
__global__ __launch_bounds__(512, 2) void fps_kernel(const float* __restrict__ ws,
                                                     float* __restrict__ out_xyz) {
    #pragma clang fp contract(off)
    const int b = blockIdx.x;
    const int tid = threadIdx.x;
    const float4* p4 = (const float4*)(ws + WS_P4) + b * Nn;

    float px[16], py[16], pz[16], dist[16];
    #pragma unroll
    for (int j = 0; j < 16; j++) {
        float4 v = p4[j * 512 + tid];    // coalesced 16B/lane
        px[j] = v.x; py[j] = v.y; pz[j] = v.z;
        dist[j] = 1e10f;                 // matches np.float32(1e10)
    }
    // Pin the working set in VGPRs: opaque to the optimizer, so the loads
    // above cannot be rematerialized inside the step loop.
    #pragma unroll
    for (int j = 0; j < 16; j++) {
        asm volatile("" : "+v"(px[j]), "+v"(py[j]), "+v"(pz[j]), "+v"(dist[j]));
    }

    __shared__ unsigned long long sKey[2][8];
    __shared__ float sHist[Sn * 3];

    // initial centroid = point 0 of the batch (uniform load, once)
    float4 c0 = p4[0];
    float cx = c0.x, cy = c0.y, cz = c0.z;

    for (int s = 0; s < Sn; s++) {
        const int par = s & 1;
        if (tid == 0) {                 // record carry centroid (LDS, cheap)
            sHist[s * 3 + 0] = cx;
            sHist[s * 3 + 1] = cy;
            sHist[s * 3 + 2] = cz;
        }
        // minimal dist update: 3 sub, 3 mul, 2 add, fmin, fmax per point —
        // exact reference op order, NO index tracking
        float lv = -1.0f;
        #pragma unroll
        for (int j = 0; j < 16; j++) {
            float dx = px[j] - cx, dy = py[j] - cy, dz = pz[j] - cz;
            float d  = (dx * dx + dy * dy) + dz * dz;
            float dm = fminf(dist[j], d);
            dist[j] = dm;
            lv = fmaxf(lv, dm);
        }
        // wave max via DPP (VALU pipe, cheap)
        float wmax = wave_fmax_dpp(lv);
        // rare-path index recovery within the wave
        int pb = 0x7fffffff;
        bool match = (lv == wmax);
        if (match) {
            #pragma unroll
            for (int j = 15; j >= 0; j--)          // descending -> min p kept
                if (dist[j] == wmax) pb = j * 512 + tid;
        }
        unsigned long long mask = __ballot(match);  // >=1 lane set
        int cand;
        if (__popcll(mask) == 1) {                  // common case
            cand = __builtin_amdgcn_readlane(pb, (int)(__ffsll(mask) - 1));
        } else {                                    // exact value tie (~rare)
            int v = pb;
            #pragma unroll
            for (int off = 32; off >= 1; off >>= 1) {
                int o = __shfl_xor(v, off);
                v = o < v ? o : v;
            }
            cand = v;
        }
        if ((tid & 63) == 0) {
            sKey[par][tid >> 6] =
                ((unsigned long long)__float_as_uint(wmax) << 32) |
                (unsigned long long)(0xFFFFFFFFu - (unsigned)cand);
        }
        __syncthreads();                   // the ONLY barrier per step
        // all threads scan the 8 wave keys: max val, min p on tie
        unsigned long long k = sKey[par][0];
        #pragma unroll
        for (int i = 1; i < 8; i++) {
            unsigned long long o = sKey[par][i];
            k = (o > k) ? o : k;
        }
        int p = (int)(0xFFFFFFFFu - (unsigned)(k & 0xFFFFFFFFull));
        float4 c4 = p4[p];                 // uniform addr -> one dwordx4, L2-hot
        cx = c4.x; cy = c4.y; cz = c4.z;
    }

    __syncthreads();                       // sHist complete
    // coalesced dump: 6144 floats = 1536 float4, 3 per thread
    float4* o4 = (float4*)(out_xyz + b * Sn * 3);
    const float4* h4 = (const float4*)sHist;
    #pragma unroll
    for (int i = tid; i < Sn * 3 / 4; i += 512) o4[i] = h4[i];
}

// ---------------------------------------------------------------------------
// Ball query, f32, mirroring the numpy transpile with einsum lowered to
// BLAS sgemm: the k=3 dot is an FMA chain acc=fma(a_k,b_k,acc) from 0.
// Norm terms are plain mul/add ((x2+y2)+z2). sq = (t1+t2) - 2*dot.
// One wave per (b,s). First K hits in ascending index order via
// ballot + prefix-popcount, early exit, pad with first hit.
// ---------------------------------------------------------------------------
__global__ __launch_bounds__(256) void ballq_kernel(const float* __restrict__ ws,
                                                    const float* __restrict__ newxyz,
                                                    int* __restrict__ grp) {
    #pragma clang fp contract(off)
    int t = blockIdx.x * 256 + threadIdx.x;
    int wid = t >> 6;            // 0..8191  (b*S+s)
    int lane = t & 63;
    int b = wid >> 11;
    const float4* p4 = (const float4*)(ws + WS_P4) + b * Nn;

    float nx = newxyz[wid * 3 + 0], ny = newxyz[wid * 3 + 1], nz = newxyz[wid * 3 + 2];
    float a2 = (nx * nx + ny * ny) + nz * nz;   // np.sum(new**2, -1): plain mul/add

    int total = 0;
    int firstp = 0;
    for (int c = 0; c < Nn / 64; c++) {
        int p = c * 64 + lane;
        float4 v = p4[p];
        float x = v.x, y = v.y, z = v.z;
        float bv = (x * x + y * y) + z * z;          // np.sum(xyz**2, -1)
        // sgemm k-loop: FMA rank-1 updates in order, acc starts at 0
        float dot = __builtin_fmaf(nx, x, 0.0f);
        dot = __builtin_fmaf(ny, y, dot);
        dot = __builtin_fmaf(nz, z, dot);
        float sq = (a2 + bv) - 2.0f * dot;           // (t1+t2) - 2*e
        bool hit = !(sq > R2c);
        unsigned long long mask = __ballot(hit);
        if (mask) {
            if (total == 0) firstp = c * 64 + (__ffsll(mask) - 1);
            int rank = __popcll(mask & ((1ull << lane) - 1ull));
            int slot = total + rank;
            if (hit && slot < Kn) grp[wid * Kn + slot] = p;
            total += (int)__popcll(mask);
            if (total >= Kn) break;
        }
    }
    if (lane >= total && lane < Kn) grp[wid * Kn + lane] = firstp;  // pad w/ first hit
}

// ---------------------------------------------------------------------------
// Fused gather + 3-layer MLP + maxpool (f32 — error ~1e-5 « 0.064 budget).
// __launch_bounds__(256, 3): 45.5 KB LDS -> 3 blocks/CU max.
// ---------------------------------------------------------------------------
template<int C, int O, int WO>
__device__ __forceinline__ void mlp_layer(const float* inT, float* outT,
                                          const float* __restrict__ wt,
                                          const float* __restrict__ bias,
                                          int kt, int ot) {
    float acc[4][WO];
    #pragma unroll
    for (int oo = 0; oo < WO; oo++) {
        float bb = bias[ot * WO + oo];
        #pragma unroll
        for (int kk = 0; kk < 4; kk++) acc[kk][oo] = bb;
    }
    for (int c = 0; c < C; c++) {
        float4 hv = *(const float4*)&inT[c * KPAD + kt * 4];
        float ha[4] = {hv.x, hv.y, hv.z, hv.w};
        const float* wp = wt + c * O + ot * WO;
        float wv[WO];
        if constexpr (WO == 2) {
            float2 w = *(const float2*)wp; wv[0] = w.x; wv[1] = w.y;
        } else if constexpr (WO == 4) {
            float4 w = *(const float4*)wp; wv[0] = w.x; wv[1] = w.y; wv[2] = w.z; wv[3] = w.w;
        } else {
            float4 w0 = *(const float4*)wp, w1 = *(const float4*)(wp + 4);
            wv[0] = w0.x; wv[1] = w0.y; wv[2] = w0.z; wv[3] = w0.w;
            wv[4] = w1.x; wv[5] = w1.y; wv[6] = w1.z; wv[7] = w1.w;
        }
        #pragma unroll
        for (int kk = 0; kk < 4; kk++)
            #pragma unroll
            for (int oo = 0; oo < WO; oo++) acc[kk][oo] += ha[kk] * wv[oo];
    }
    #pragma unroll
    for (int oo = 0; oo < WO; oo++) {
        int o = ot * WO + oo;
        float4 st;
        st.x = fmaxf(acc[0][oo], 0.f); st.y = fmaxf(acc[1][oo], 0.f);
        st.z = fmaxf(acc[2][oo], 0.f); st.w = fmaxf(acc[3][oo], 0.f);
        *(float4*)&outT[o * KPAD + kt * 4] = st;
    }
}

__global__ __launch_bounds__(256, 3) void mlp_kernel(const float* __restrict__ xyz,
                                                     const float* __restrict__ feat,
                                                     const float* __restrict__ ws,
                                                     const int* __restrict__ grp,
                                                     const float* __restrict__ b1,
                                                     const float* __restrict__ b2,
                                                     const float* __restrict__ b3,
                                                     float* __restrict__ out) {
    __shared__ float h0[67 * KPAD];
    __shared__ float h1[64 * KPAD];
    __shared__ float h2[128 * KPAD];
    __shared__ float mxs[8 * 256];
    __shared__ int   sIdx[Kn];
    __shared__ float sCent[3];

    int g = blockIdx.x;            // b*S + s
    int b = g >> 11;
    int tid = threadIdx.x;

    if (tid < Kn) sIdx[tid] = grp[g * Kn + tid];
    if (tid == 0) { sCent[0] = out[g*3]; sCent[1] = out[g*3+1]; sCent[2] = out[g*3+2]; }
    __syncthreads();

    { // gather: 8 threads per neighbor row
        int k = tid >> 3, m = tid & 7;
        int idx = sIdx[k];
        int base = b * Nn + idx;
        if (m == 0) {
            h0[0 * KPAD + k] = xyz[base * 3 + 0] - sCent[0];
            h0[1 * KPAD + k] = xyz[base * 3 + 1] - sCent[1];
            h0[2 * KPAD + k] = xyz[base * 3 + 2] - sCent[2];
        }
        const float4* f4 = (const float4*)(feat + base * 64 + m * 8);
        float4 a = f4[0], c4 = f4[1];
        int r = 3 + m * 8;
        h0[(r + 0) * KPAD + k] = a.x;  h0[(r + 1) * KPAD + k] = a.y;
        h0[(r + 2) * KPAD + k] = a.z;  h0[(r + 3) * KPAD + k] = a.w;
        h0[(r + 4) * KPAD + k] = c4.x; h0[(r + 5) * KPAD + k] = c4.y;
        h0[(r + 6) * KPAD + k] = c4.z; h0[(r + 7) * KPAD + k] = c4.w;
    }
    __syncthreads();

    int ot = tid & 31, kt = tid >> 5;

    mlp_layer<67, 64, 2>(h0, h1, ws + WS_W1T, b1, kt, ot);
    __syncthreads();
    mlp_layer<64, 128, 4>(h1, h2, ws + WS_W2T, b2, kt, ot);
    __syncthreads();

    { // L3 (128 -> 256) fused with maxpool over the thread's 4 k-rows
        float acc[4][8];
        #pragma unroll
        for (int oo = 0; oo < 8; oo++) {
            float bb = b3[ot * 8 + oo];
            #pragma unroll
            for (int kk = 0; kk < 4; kk++) acc[kk][oo] = bb;
        }
        const float* wt = ws + WS_W3T;
        for (int c = 0; c < 128; c++) {
            float4 hv = *(const float4*)&h2[c * KPAD + kt * 4];
            float ha[4] = {hv.x, hv.y, hv.z, hv.w};
            const float* wp = wt + c * 256 + ot * 8;
            float4 w0 = *(const float4*)wp, w1 = *(const float4*)(wp + 4);
            float wv[8] = {w0.x, w0.y, w0.z, w0.w, w1.x, w1.y, w1.z, w1.w};
            #pragma unroll
            for (int kk = 0; kk < 4; kk++)
                #pragma unroll
                for (int oo = 0; oo < 8; oo++) acc[kk][oo] += ha[kk] * wv[oo];
        }
        #pragma unroll
        for (int oo = 0; oo < 8; oo++) {
            float m = fmaxf(fmaxf(acc[0][oo], acc[1][oo]), fmaxf(acc[2][oo], acc[3][oo]));
            mxs[kt * 256 + ot * 8 + oo] = fmaxf(m, 0.f);   // relu(max) == max(relu)
        }
    }
    __syncthreads();

    { // reduce the 8 k-tiles, write feats
        int o = tid;
        float m = mxs[o];
        #pragma unroll
        for (int q = 1; q < 8; q++) m = fmaxf(m, mxs[q * 256 + o]);
        out[OUT_XYZ + g * 256 + o] = m;
    }
}

// ---------------------------------------------------------------------------
extern "C" void kernel_launch(void* const* d_in, const int* in_sizes, int n_in,
                              void* d_out, int out_size, void* d_ws, size_t ws_size,
                              hipStream_t stream) {
    const float* xyz  = (const float*)d_in[0];
    const float* feat = (const float*)d_in[1];
    const float* W1   = (const float*)d_in[2];
    const float* b1   = (const float*)d_in[3];
    const float* W2   = (const float*)d_in[4];
    const float* b2   = (const float*)d_in[5];
    const float* W3   = (const float*)d_in[6];
    const float* b3   = (const float*)d_in[7];
    float* out = (float*)d_out;
    float* ws  = (float*)d_ws;
    int*   grp = (int*)d_ws + WS_GRP;

    hipLaunchKernelGGL(prep_kernel, dim3(305), dim3(256), 0, stream, xyz, W1, W2, W3, ws);
    hipLaunchKernelGGL(fps_kernel, dim3(Bn), dim3(512), 0, stream, ws, out);
    hipLaunchKernelGGL(ballq_kernel, dim3(Bn * Sn / 4), dim3(256), 0, stream, ws, out, grp);
    hipLaunchKernelGGL(mlp_kernel, dim3(Bn * Sn), dim3(256), 0, stream,
                       xyz, feat, ws, grp, b1, b2, b3, out);
}